// Round 1
// 188.220 us; speedup vs baseline: 1.2061x; 1.2061x over previous
//
#include <hip/hip_runtime.h>
#include <math.h>

// ---------------------------------------------------------------------------
// 2-layer GCN, commuted both layers:
//   h2  = relu((M·X)@W1 + b1) @ W2          (one fused kernel, f16 MFMA GEMMs)
//   out = M·h2 + b2                         (pure 64-wide gather kernel)
// M = D^-1/2 (A+I) D^-1/2.  All staged tensors f16 (better than bf16 AND
// MFMA-capable).  W1/W2 pre-packed into per-lane MFMA B-fragments in prep.
// CSR built per call: (convert|histogram|Wpack) -> chained scan -> scatter.
// ---------------------------------------------------------------------------

#define SCAN_CHUNK 8192
#define RPB 32                      // node rows per fused block

typedef _Float16 h8  __attribute__((ext_vector_type(8)));
typedef _Float16 h2t __attribute__((ext_vector_type(2)));
typedef float    f4v __attribute__((ext_vector_type(4)));

__device__ __forceinline__ unsigned pkh(float a, float b) {
    auto r = __builtin_amdgcn_cvt_pkrtz(a, b);          // 2xf32 -> packed f16 (RTZ)
    return __builtin_bit_cast(unsigned, r);
}
__device__ __forceinline__ void accw(float* g, float c, unsigned w) {
    h2t p = __builtin_bit_cast(h2t, w);
    g[0] += c * (float)p.x;
    g[1] += c * (float)p.y;
}
__device__ __forceinline__ void acc16h(float* ga, float c, uint4 u0, uint4 u1) {
    accw(ga + 0, c, u0.x); accw(ga + 2, c, u0.y);
    accw(ga + 4, c, u0.z); accw(ga + 6, c, u0.w);
    accw(ga + 8, c, u1.x); accw(ga + 10, c, u1.y);
    accw(ga + 12, c, u1.z); accw(ga + 14, c, u1.w);
}
__device__ __forceinline__ void acc8h(float* ga, float c, uint4 u) {
    accw(ga + 0, c, u.x); accw(ga + 2, c, u.y);
    accw(ga + 4, c, u.z); accw(ga + 6, c, u.w);
}

// blocks [0,CB): convert x->f16 (8/thread); [CB,CB+EB): degree histogram;
// [CB+EB,+8): pack W1 frags; [+8,+12): pack W2 frags.
// B-frag layout (16x16x32): lane l, j=0..7 holds W[kt*32+(l>>4)*8+j][nt*16+(l&15)],
// stored at frag base ((kt*NT+nt)*64+l)*8 so a fragment load is one b128/lane.
__global__ __launch_bounds__(256) void k_prep(const float* __restrict__ x,
                                              unsigned short* __restrict__ xh, int nElem,
                                              const int* __restrict__ dst, int* cnt,
                                              int* __restrict__ epos, int e, int CB, int EB,
                                              const float* __restrict__ W1,
                                              const float* __restrict__ W2,
                                              unsigned short* __restrict__ Wpk1,
                                              unsigned short* __restrict__ Wpk2) {
    const int blk = (int)blockIdx.x;
    if (blk < CB) {
        int i8 = (blk * 256 + threadIdx.x) * 8;
        if (i8 < nElem) {
            float4 v0 = *(const float4*)&x[i8];
            float4 v1 = *(const float4*)&x[i8 + 4];
            uint4 o;
            o.x = pkh(v0.x, v0.y); o.y = pkh(v0.z, v0.w);
            o.z = pkh(v1.x, v1.y); o.w = pkh(v1.z, v1.w);
            *(uint4*)&xh[i8] = o;
        }
    } else if (blk < CB + EB) {
        int i = (blk - CB) * 256 + threadIdx.x;
        if (i < e) epos[i] = atomicAdd(&cnt[dst[i]], 1);
    } else if (blk < CB + EB + 8) {
        int idx = (blk - CB - EB) * 256 + threadIdx.x;     // [0,2048)
        int l = idx & 63, g = idx >> 6;                    // g in [0,32)
        int kt = g >> 3, nt = g & 7;
        const float* Wp = W1 + (size_t)(kt * 32 + ((l >> 4) << 3)) * 128 + nt * 16 + (l & 15);
        uint4 o;
        o.x = pkh(Wp[0],   Wp[128]);
        o.y = pkh(Wp[256], Wp[384]);
        o.z = pkh(Wp[512], Wp[640]);
        o.w = pkh(Wp[768], Wp[896]);
        *(uint4*)&Wpk1[(size_t)idx * 8] = o;
    } else {
        int idx = (blk - CB - EB - 8) * 256 + threadIdx.x; // [0,1024)
        if (idx < 1024) {
            int l = idx & 63, g = idx >> 6;                // g in [0,16)
            int kt = g >> 2, nt = g & 3;
            const float* Wp = W2 + (size_t)(kt * 32 + ((l >> 4) << 3)) * 64 + nt * 16 + (l & 15);
            uint4 o;
            o.x = pkh(Wp[0],   Wp[64]);
            o.y = pkh(Wp[128], Wp[192]);
            o.z = pkh(Wp[256], Wp[320]);
            o.w = pkh(Wp[384], Wp[448]);
            *(uint4*)&Wpk2[(size_t)idx * 8] = o;
        }
    }
}

// Single-kernel chained exclusive scan (nb blocks, 8192 elems each); emits dinv.
__global__ __launch_bounds__(256) void k_scan1(const int* __restrict__ cnt,
                                               int* __restrict__ rowptr, float* __restrict__ dinv,
                                               int* __restrict__ flg, int* __restrict__ incl,
                                               int n, int nb) {
    __shared__ int part[256];
    __shared__ int sPrev;
    const int t   = threadIdx.x;
    const int blk = blockIdx.x;
    const int base = blk * SCAN_CHUNK + t * 32;
    int v[32];
    int s = 0;
#pragma unroll
    for (int q = 0; q < 32; ++q) {
        int i = base + q;
        v[q] = (i < n) ? cnt[i] : 0;
        s += v[q];
    }
    part[t] = s;
    __syncthreads();
    for (int off = 1; off < 256; off <<= 1) {
        int u = (t >= off) ? part[t - off] : 0;
        __syncthreads();
        part[t] += u;
        __syncthreads();
    }
    if (t == 0) {
        int prev = 0;
        if (blk > 0) {
            while (__hip_atomic_load(&flg[blk - 1], __ATOMIC_ACQUIRE, __HIP_MEMORY_SCOPE_AGENT) == 0) {}
            prev = __hip_atomic_load(&incl[blk - 1], __ATOMIC_RELAXED, __HIP_MEMORY_SCOPE_AGENT);
        }
        const int total = part[255];
        __hip_atomic_store(&incl[blk], prev + total, __ATOMIC_RELAXED, __HIP_MEMORY_SCOPE_AGENT);
        __hip_atomic_store(&flg[blk], 1, __ATOMIC_RELEASE, __HIP_MEMORY_SCOPE_AGENT);
        if (blk == nb - 1) rowptr[n] = prev + total;
        sPrev = prev;
    }
    __syncthreads();
    int run = sPrev + part[t] - s;
#pragma unroll
    for (int q = 0; q < 32; ++q) {
        int i = base + q;
        if (i < n) {
            rowptr[i] = run;
            dinv[i]   = rsqrtf((float)(v[q] + 1));   // +1 self-loop
            run += v[q];
        }
    }
}

// Packed edge records sorted by dst: (src, dinv[src]*dinv[dst])
__global__ __launch_bounds__(256) void k_fill(const int* __restrict__ src, const int* __restrict__ dst,
                                              const int* __restrict__ rowptr, const int* __restrict__ epos,
                                              const float* __restrict__ dinv,
                                              int2* __restrict__ erec, int e) {
    int i = blockIdx.x * blockDim.x + threadIdx.x;
    if (i < e) {
        int d = dst[i];
        int s = src[i];
        erec[rowptr[d] + epos[i]] = make_int2(s, __float_as_int(dinv[s] * dinv[d]));
    }
}

// ---------------------------------------------------------------------------
// Fused layer-1 + W2 commute.  32 rows/block, 256 thr (4 waves).
// Phase A: register gather (8 lanes/row, 16 f16 feats/lane, 4-wide branch-free
//          edge pipeline) -> f16 into swizzled LDS tile sM[32][128].
// Phase B: MFMA (M·X)@W1: wave w owns cols [32w,32w+32); A-frags from LDS
//          (b128, XOR-16 swizzle => conflict-free), B-frags from global Wpk1.
// Phase C: +b1, relu, write a1 back to the same LDS tile (f16, same swizzle).
// Phase D: MFMA a1@W2 -> h2 (f16, N x 64) to global.
// LDS swizzle: byte ^= (row&7)<<4 applied to final address (write & read).
// ---------------------------------------------------------------------------
__global__ __launch_bounds__(256, 4) void fused_l1(const unsigned short* __restrict__ Xh,
                                                   const unsigned short* __restrict__ Wpk1,
                                                   const float* __restrict__ bias1,
                                                   const unsigned short* __restrict__ Wpk2,
                                                   const int* __restrict__ rowptr,
                                                   const int2* __restrict__ erec,
                                                   const float* __restrict__ dinv,
                                                   unsigned short* __restrict__ h2,
                                                   int n) {
    __shared__ __align__(16) char sMb[RPB * 256];    // 32 rows x 128 f16 = 8 KB

    const int t    = threadIdx.x;
    const int row0 = blockIdx.x * RPB;

    // ---- Phase A: gather ----
    {
        const int r = t >> 3;                 // row-in-block 0..31
        const int b = t & 7;                  // lane-in-row  0..7 (16 feats each)
        const int d = row0 + r;
        float ga[16] = {};
        if (d < n) {
            const float wd = dinv[d];
            const uint4* P = (const uint4*)(Xh + ((size_t)d << 7)) + b * 2;
            acc16h(ga, wd * wd, P[0], P[1]);
            const int beg = rowptr[d], end = rowptr[d + 1];
            int j = beg;
            const int2 Z = make_int2(0, 0);
            int2 r0 = (j     < end) ? erec[j]     : Z;
            int2 r1 = (j + 1 < end) ? erec[j + 1] : Z;
            int2 r2 = (j + 2 < end) ? erec[j + 2] : Z;
            int2 r3 = (j + 3 < end) ? erec[j + 3] : Z;
            while (j < end) {
                const int2 c0 = r0, c1 = r1, c2 = r2, c3 = r3;
                const int jn = j + 4;
                r0 = (jn     < end) ? erec[jn]     : Z;   // prefetch next quad
                r1 = (jn + 1 < end) ? erec[jn + 1] : Z;
                r2 = (jn + 2 < end) ? erec[jn + 2] : Z;
                r3 = (jn + 3 < end) ? erec[jn + 3] : Z;
                const uint4* P0 = (const uint4*)(Xh + ((size_t)c0.x << 7)) + b * 2;
                const uint4* P1 = (const uint4*)(Xh + ((size_t)c1.x << 7)) + b * 2;
                const uint4* P2 = (const uint4*)(Xh + ((size_t)c2.x << 7)) + b * 2;
                const uint4* P3 = (const uint4*)(Xh + ((size_t)c3.x << 7)) + b * 2;
                uint4 a0 = P0[0], a1 = P0[1];
                uint4 b0 = P1[0], b1 = P1[1];
                uint4 d0 = P2[0], d1 = P2[1];
                uint4 e0 = P3[0], e1 = P3[1];
                acc16h(ga, __int_as_float(c0.y), a0, a1);  // coef 0 for tail slots
                acc16h(ga, __int_as_float(c1.y), b0, b1);
                acc16h(ga, __int_as_float(c2.y), d0, d1);
                acc16h(ga, __int_as_float(c3.y), e0, e1);
                j = jn;
            }
        }
        uint4 o0, o1;
        o0.x = pkh(ga[0],  ga[1]);  o0.y = pkh(ga[2],  ga[3]);
        o0.z = pkh(ga[4],  ga[5]);  o0.w = pkh(ga[6],  ga[7]);
        o1.x = pkh(ga[8],  ga[9]);  o1.y = pkh(ga[10], ga[11]);
        o1.z = pkh(ga[12], ga[13]); o1.w = pkh(ga[14], ga[15]);
        const int swz = (r & 7) << 4;
        *(uint4*)(sMb + ((r * 256 + b * 32)      ^ swz)) = o0;
        *(uint4*)(sMb + ((r * 256 + b * 32 + 16) ^ swz)) = o1;
    }
    __syncthreads();

    const int w  = t >> 6;                    // wave 0..3
    const int l  = t & 63;
    const int lr = l & 15;                    // frag row/col within 16-tile
    const int lk = (l >> 4) << 4;             // byte offset of this lane's k-octet
    const int sz = (lr & 7) << 4;             // swizzle for rows lr and lr+16

    // ---- Phase B: (M·X)@W1, wave w -> cols [32w, 32w+32) ----
    f4v acc[2][2] = {};
#pragma unroll
    for (int kt = 0; kt < 4; ++kt) {
        const int kb = kt * 64 + lk;
        h8 a0 = *(const h8*)(sMb + ((lr * 256 + kb)        ^ sz));
        h8 a1 = *(const h8*)(sMb + (((lr + 16) * 256 + kb) ^ sz));
        const h8* Bp = (const h8*)Wpk1 + (kt * 8 + w * 2) * 64 + l;
        h8 b0 = Bp[0];
        h8 b1 = Bp[64];
        acc[0][0] = __builtin_amdgcn_mfma_f32_16x16x32_f16(a0, b0, acc[0][0], 0, 0, 0);
        acc[0][1] = __builtin_amdgcn_mfma_f32_16x16x32_f16(a0, b1, acc[0][1], 0, 0, 0);
        acc[1][0] = __builtin_amdgcn_mfma_f32_16x16x32_f16(a1, b0, acc[1][0], 0, 0, 0);
        acc[1][1] = __builtin_amdgcn_mfma_f32_16x16x32_f16(a1, b1, acc[1][1], 0, 0, 0);
    }
    __syncthreads();                          // all sM reads done before a1 overwrite

    // ---- Phase C: bias+relu -> a1 (f16) back into the same LDS tile ----
    {
        const float bb0 = bias1[w * 32 + lr];
        const float bb1 = bias1[w * 32 + 16 + lr];
        const int c0 = (w * 32 + lr) * 2;
        const int c1 = (w * 32 + 16 + lr) * 2;
#pragma unroll
        for (int mt = 0; mt < 2; ++mt)
#pragma unroll
            for (int v = 0; v < 4; ++v) {
                const int row = mt * 16 + ((l >> 4) << 2) + v;
                const int rs  = (row & 7) << 4;
                float o0 = fmaxf(acc[mt][0][v] + bb0, 0.f);
                float o1 = fmaxf(acc[mt][1][v] + bb1, 0.f);
                *(_Float16*)(sMb + ((row * 256 + c0) ^ rs)) = (_Float16)o0;
                *(_Float16*)(sMb + ((row * 256 + c1) ^ rs)) = (_Float16)o1;
            }
    }
    __syncthreads();

    // ---- Phase D: a1@W2 -> h2, wave w -> cols [16w, 16w+16) ----
    f4v acc2[2] = {};
#pragma unroll
    for (int kt = 0; kt < 4; ++kt) {
        const int kb = kt * 64 + lk;
        h8 a0 = *(const h8*)(sMb + ((lr * 256 + kb)        ^ sz));
        h8 a1 = *(const h8*)(sMb + (((lr + 16) * 256 + kb) ^ sz));
        h8 b  = *((const h8*)Wpk2 + (kt * 4 + w) * 64 + l);
        acc2[0] = __builtin_amdgcn_mfma_f32_16x16x32_f16(a0, b, acc2[0], 0, 0, 0);
        acc2[1] = __builtin_amdgcn_mfma_f32_16x16x32_f16(a1, b, acc2[1], 0, 0, 0);
    }
#pragma unroll
    for (int mt = 0; mt < 2; ++mt)
#pragma unroll
        for (int v = 0; v < 4; ++v) {
            const int row = row0 + mt * 16 + ((l >> 4) << 2) + v;
            if (row < n) {
                _Float16 hv = (_Float16)acc2[mt][v];
                h2[(size_t)row * 64 + w * 16 + lr] = __builtin_bit_cast(unsigned short, hv);
            }
        }
}

// ---------------------------------------------------------------------------
// Layer-2 aggregation: out[d] = dinv_d^2*h2[d] + sum_e coef_e*h2[src_e] + b2.
// Pure 64-wide gather (128 B/row): 8 lanes/row, 1 uint4 (8 f16) per lane.
// ---------------------------------------------------------------------------
__global__ __launch_bounds__(256, 6) void k_out(const unsigned short* __restrict__ h2,
                                                const float* __restrict__ b2,
                                                const int* __restrict__ rowptr,
                                                const int2* __restrict__ erec,
                                                const float* __restrict__ dinv,
                                                float* __restrict__ out, int n) {
    const int t = threadIdx.x;
    const int r = t >> 3;
    const int b = t & 7;
    const int d = blockIdx.x * RPB + r;
    if (d >= n) return;

    float ga[8] = {};
    {
        const float wd = dinv[d];
        uint4 u = *((const uint4*)(h2 + ((size_t)d << 6)) + b);
        acc8h(ga, wd * wd, u);
    }
    const int beg = rowptr[d], end = rowptr[d + 1];
    int j = beg;
    const int2 Z = make_int2(0, 0);
    int2 r0 = (j     < end) ? erec[j]     : Z;
    int2 r1 = (j + 1 < end) ? erec[j + 1] : Z;
    int2 r2 = (j + 2 < end) ? erec[j + 2] : Z;
    int2 r3 = (j + 3 < end) ? erec[j + 3] : Z;
    while (j < end) {
        const int2 c0 = r0, c1 = r1, c2 = r2, c3 = r3;
        const int jn = j + 4;
        r0 = (jn     < end) ? erec[jn]     : Z;
        r1 = (jn + 1 < end) ? erec[jn + 1] : Z;
        r2 = (jn + 2 < end) ? erec[jn + 2] : Z;
        r3 = (jn + 3 < end) ? erec[jn + 3] : Z;
        uint4 a = *((const uint4*)(h2 + ((size_t)c0.x << 6)) + b);
        uint4 u1 = *((const uint4*)(h2 + ((size_t)c1.x << 6)) + b);
        uint4 u2 = *((const uint4*)(h2 + ((size_t)c2.x << 6)) + b);
        uint4 u3 = *((const uint4*)(h2 + ((size_t)c3.x << 6)) + b);
        acc8h(ga, __int_as_float(c0.y), a);
        acc8h(ga, __int_as_float(c1.y), u1);
        acc8h(ga, __int_as_float(c2.y), u2);
        acc8h(ga, __int_as_float(c3.y), u3);
        j = jn;
    }
    const float4 bv0 = *(const float4*)&b2[b * 8];
    const float4 bv1 = *(const float4*)&b2[b * 8 + 4];
    float* O = out + (size_t)d * 64 + b * 8;
    *(float4*)O       = make_float4(ga[0] + bv0.x, ga[1] + bv0.y, ga[2] + bv0.z, ga[3] + bv0.w);
    *(float4*)(O + 4) = make_float4(ga[4] + bv1.x, ga[5] + bv1.y, ga[6] + bv1.z, ga[7] + bv1.w);
}

// ---------------------------------------------------------------------------

extern "C" void kernel_launch(void* const* d_in, const int* in_sizes, int n_in,
                              void* d_out, int out_size, void* d_ws, size_t ws_size,
                              hipStream_t stream) {
    const float* x  = (const float*)d_in[0];
    const int*   ei = (const int*)d_in[1];
    const float* W1 = (const float*)d_in[2];
    const float* b1 = (const float*)d_in[3];
    const float* W2 = (const float*)d_in[4];
    const float* b2 = (const float*)d_in[5];
    float* out = (float*)d_out;

    const int N = in_sizes[0] / 128;
    const int E = in_sizes[1] / 2;
    const int* src = ei;
    const int* dst = ei + E;
    const int NB = (N + SCAN_CHUNK - 1) / SCAN_CHUNK;   // 7 for N=50000

    // workspace carve (256B aligned)
    size_t off = 0;
    char* base = (char*)d_ws;
    auto carve = [&](size_t bytes) -> void* {
        void* p = base + off;
        off += (bytes + 255) & ~(size_t)255;
        return p;
    };
    int*   cnt    = (int*)carve((size_t)N * 4);         // | zeroed as one span
    int*   flg    = (int*)carve((size_t)NB * 4);        // |
    int*   incl   = (int*)carve((size_t)NB * 4);        // |
    size_t zspan  = off;
    int*   rowptr = (int*)carve((size_t)(N + 1) * 4);
    float* dinv   = (float*)carve((size_t)N * 4);
    int2*  erec   = (int2*)carve((size_t)E * 8);
    unsigned short* xh   = (unsigned short*)carve((size_t)N * 128 * 2);
    unsigned short* h2   = (unsigned short*)carve((size_t)N * 64 * 2);
    unsigned short* Wpk1 = (unsigned short*)carve(128 * 128 * 2);
    unsigned short* Wpk2 = (unsigned short*)carve(128 * 64 * 2);
    int*   epos   = (int*)h2;   // alias: epos dead before h2 is written (fused_l1)

    if (off > ws_size) return;  // diagnostic guard

    // 1) f16 convert + degree histogram + W frag-pack (one launch), scan, scatter
    const int nElem = N * 128;
    const int CB = (nElem / 8 + 255) / 256;
    const int EB = (E + 255) / 256;
    hipMemsetAsync(cnt, 0, zspan, stream);
    k_prep <<<CB + EB + 12, 256, 0, stream>>>(x, xh, nElem, dst, cnt, epos, E, CB, EB,
                                              W1, W2, Wpk1, Wpk2);
    k_scan1<<<NB, 256, 0, stream>>>(cnt, rowptr, dinv, flg, incl, N, NB);
    k_fill <<<(E + 255) / 256, 256, 0, stream>>>(src, dst, rowptr, epos, dinv, erec, E);

    const int nblk = (N + RPB - 1) / RPB;
    // 2) fused layer 1 (+W2 commute): h2 = f16(relu((M xh)@W1 + b1) @ W2)
    fused_l1<<<nblk, 256, 0, stream>>>(xh, Wpk1, b1, Wpk2, rowptr, erec, dinv, h2, N);
    // 3) layer 2 aggregation: out = (M h2) + b2   (fp32 out)
    k_out<<<nblk, 256, 0, stream>>>(h2, b2, rowptr, erec, dinv, out, N);
}

// Round 2
// 160.667 us; speedup vs baseline: 1.4130x; 1.1715x over previous
//
#include <hip/hip_runtime.h>
#include <math.h>

// ---------------------------------------------------------------------------
// 2-layer GCN, commuted both layers:
//   h2  = relu((M·X)@W1 + b1) @ W2          (one fused kernel, f16 MFMA GEMMs)
//   out = M·h2 + b2                         (pure 64-wide gather kernel)
// M = D^-1/2 (A+I) D^-1/2.  All staged tensors f16.
// CSR build: two-level bucket sort (dst>>8) -- LDS atomics + ~31K global
// reservation atomics instead of 625K memory-side per-edge atomics.
//   k_prep:   convert x->f16 | bucket phase A (LDS hist + reserve + scatter
//             to fixed-capacity bucket regions) | W1/W2 MFMA-frag pack
//   k_bucket: per-bucket local sort -> rowptr, dinv, erec (src,dst)
//   k_coef:   erec (src,dst) -> (src, dinv[s]*dinv[d])
// ---------------------------------------------------------------------------

#define RPB 32                      // node rows per fused block
#define CAP 8192                    // edge capacity per 256-dst bucket (avg ~3190)
#define PA_BLK 160                  // phase-A bucket blocks

typedef _Float16 h8  __attribute__((ext_vector_type(8)));
typedef _Float16 h2t __attribute__((ext_vector_type(2)));
typedef float    f4v __attribute__((ext_vector_type(4)));

__device__ __forceinline__ unsigned pkh(float a, float b) {
    auto r = __builtin_amdgcn_cvt_pkrtz(a, b);          // 2xf32 -> packed f16 (RTZ)
    return __builtin_bit_cast(unsigned, r);
}
__device__ __forceinline__ void accw(float* g, float c, unsigned w) {
    h2t p = __builtin_bit_cast(h2t, w);
    g[0] += c * (float)p.x;
    g[1] += c * (float)p.y;
}
__device__ __forceinline__ void acc16h(float* ga, float c, uint4 u0, uint4 u1) {
    accw(ga + 0, c, u0.x); accw(ga + 2, c, u0.y);
    accw(ga + 4, c, u0.z); accw(ga + 6, c, u0.w);
    accw(ga + 8, c, u1.x); accw(ga + 10, c, u1.y);
    accw(ga + 12, c, u1.z); accw(ga + 14, c, u1.w);
}
__device__ __forceinline__ void acc8h(float* ga, float c, uint4 u) {
    accw(ga + 0, c, u.x); accw(ga + 2, c, u.y);
    accw(ga + 4, c, u.z); accw(ga + 6, c, u.w);
}

// blocks [0,CB): convert x->f16 (8/thread); [CB,CB+PA): bucket phase A;
// [CB+PA,+8): pack W1 frags; [+8,+12): pack W2 frags.
// B-frag layout (16x16x32): lane l, j=0..7 holds W[kt*32+(l>>4)*8+j][nt*16+(l&15)],
// stored at frag base ((kt*NT+nt)*64+l)*8 so a fragment load is one b128/lane.
__global__ __launch_bounds__(256) void k_prep(const float* __restrict__ x,
                                              unsigned short* __restrict__ xh, int nElem,
                                              const int* __restrict__ src,
                                              const int* __restrict__ dst, int e,
                                              int* __restrict__ bcur,
                                              int2* __restrict__ ebuf,
                                              int CB, int EPB,
                                              const float* __restrict__ W1,
                                              const float* __restrict__ W2,
                                              unsigned short* __restrict__ Wpk1,
                                              unsigned short* __restrict__ Wpk2) {
    const int blk = (int)blockIdx.x;
    if (blk < CB) {
        int i8 = (blk * 256 + threadIdx.x) * 8;
        if (i8 < nElem) {
            float4 v0 = *(const float4*)&x[i8];
            float4 v1 = *(const float4*)&x[i8 + 4];
            uint4 o;
            o.x = pkh(v0.x, v0.y); o.y = pkh(v0.z, v0.w);
            o.z = pkh(v1.x, v1.y); o.w = pkh(v1.z, v1.w);
            *(uint4*)&xh[i8] = o;
        }
    } else if (blk < CB + PA_BLK) {
        __shared__ int h[256];          // per-bucket count, then local cursor
        __shared__ int gb[256];         // reserved global base per bucket
        const int t = threadIdx.x;
        h[t] = 0;
        __syncthreads();
        const int e0 = (blk - CB) * EPB;
        const int e1 = min(e0 + EPB, e);
        for (int i = e0 + t; i < e1; i += 256)
            atomicAdd(&h[((unsigned)dst[i]) >> 8], 1);              // LDS
        __syncthreads();
        const int c = h[t];
        if (c > 0) gb[t] = atomicAdd(&bcur[t], c);                  // global reserve
        h[t] = 0;
        __syncthreads();
        for (int i = e0 + t; i < e1; i += 256) {
            const int d  = dst[i];
            const int bk = ((unsigned)d) >> 8;
            const int p  = atomicAdd(&h[bk], 1) + gb[bk];           // LDS rank
            if (p < CAP) ebuf[((size_t)bk << 13) + p] = make_int2(src[i], d);
        }
    } else if (blk < CB + PA_BLK + 8) {
        int idx = (blk - CB - PA_BLK) * 256 + threadIdx.x;     // [0,2048)
        int l = idx & 63, g = idx >> 6;                        // g in [0,32)
        int kt = g >> 3, nt = g & 7;
        const float* Wp = W1 + (size_t)(kt * 32 + ((l >> 4) << 3)) * 128 + nt * 16 + (l & 15);
        uint4 o;
        o.x = pkh(Wp[0],   Wp[128]);
        o.y = pkh(Wp[256], Wp[384]);
        o.z = pkh(Wp[512], Wp[640]);
        o.w = pkh(Wp[768], Wp[896]);
        *(uint4*)&Wpk1[(size_t)idx * 8] = o;
    } else {
        int idx = (blk - CB - PA_BLK - 8) * 256 + threadIdx.x; // [0,1024)
        if (idx < 1024) {
            int l = idx & 63, g = idx >> 6;                    // g in [0,16)
            int kt = g >> 2, nt = g & 3;
            const float* Wp = W2 + (size_t)(kt * 32 + ((l >> 4) << 3)) * 64 + nt * 16 + (l & 15);
            uint4 o;
            o.x = pkh(Wp[0],   Wp[64]);
            o.y = pkh(Wp[128], Wp[192]);
            o.z = pkh(Wp[256], Wp[320]);
            o.w = pkh(Wp[384], Wp[448]);
            *(uint4*)&Wpk2[(size_t)idx * 8] = o;
        }
    }
}

// One block per 256-dst bucket: per-dst hist -> degrees/dinv/rowptr; scatter
// bucket edges to final dst-sorted erec positions. Bucket bases from a
// redundant 256-wide LDS scan of bcur.
__global__ __launch_bounds__(256) void k_bucket(const int2* __restrict__ ebuf,
                                                const int* __restrict__ bcur,
                                                int* __restrict__ rowptr,
                                                float* __restrict__ dinv,
                                                int2* __restrict__ erec,
                                                int n, int nbk, int e) {
    __shared__ int sc[256];
    __shared__ int h[256];
    __shared__ int loc[256];
    __shared__ int sBase;
    const int t = threadIdx.x;
    const int b = blockIdx.x;

    // bucket base = exclusive scan of (clamped) bucket totals at b
    const int v = (t < nbk) ? min(bcur[t], CAP) : 0;
    sc[t] = v;
    __syncthreads();
    for (int off = 1; off < 256; off <<= 1) {
        int u = (t >= off) ? sc[t - off] : 0;
        __syncthreads();
        sc[t] += u;
        __syncthreads();
    }
    if (t == b) sBase = sc[t] - v;
    if (b == 0 && t == 0) rowptr[n] = e;
    h[t] = 0;
    __syncthreads();

    const int cb = min(bcur[b], CAP);
    const int2* __restrict__ eb = ebuf + ((size_t)b << 13);
    for (int i = t; i < cb; i += 256) atomicAdd(&h[eb[i].y & 255], 1);
    __syncthreads();
    const int deg = h[t];
    sc[t] = deg;
    __syncthreads();
    for (int off = 1; off < 256; off <<= 1) {
        int u = (t >= off) ? sc[t - off] : 0;
        __syncthreads();
        sc[t] += u;
        __syncthreads();
    }
    loc[t] = sc[t] - deg;                  // local exclusive offset
    const int id = (b << 8) + t;
    if (id < n) {
        rowptr[id] = sBase + loc[t];
        dinv[id]   = rsqrtf((float)(deg + 1));   // +1 self-loop
    }
    h[t] = 0;                              // per-dst cursor
    __syncthreads();
    int2* __restrict__ outp = erec + sBase;
    for (int i = t; i < cb; i += 256) {
        const int2 r  = eb[i];
        const int  lb = r.y & 255;
        const int  p  = atomicAdd(&h[lb], 1);
        outp[loc[lb] + p] = r;
    }
}

// (src,dst) -> (src, dinv[src]*dinv[dst]) in place
__global__ __launch_bounds__(256) void k_coef(int2* __restrict__ erec,
                                              const float* __restrict__ dinv, int e) {
    int i = blockIdx.x * 256 + threadIdx.x;
    if (i < e) {
        int2 r = erec[i];
        erec[i] = make_int2(r.x, __float_as_int(dinv[r.x] * dinv[r.y]));
    }
}

// ---------------------------------------------------------------------------
// Fused layer-1 + W2 commute.  32 rows/block, 256 thr (4 waves).
// Phase A: register gather (8 lanes/row, 16 f16 feats/lane, 4-wide branch-free
//          edge pipeline) -> f16 into swizzled LDS tile sM[32][128].
// Phase B: MFMA (M·X)@W1: wave w owns cols [32w,32w+32); A-frags from LDS
//          (b128, XOR-16 swizzle => conflict-free), B-frags from global Wpk1.
// Phase C: +b1, relu, write a1 back to the same LDS tile (f16, same swizzle).
// Phase D: MFMA a1@W2 -> h2 (f16, N x 64) to global.
// LDS swizzle: byte ^= (row&7)<<4 applied to final address (write & read).
// ---------------------------------------------------------------------------
__global__ __launch_bounds__(256, 4) void fused_l1(const unsigned short* __restrict__ Xh,
                                                   const unsigned short* __restrict__ Wpk1,
                                                   const float* __restrict__ bias1,
                                                   const unsigned short* __restrict__ Wpk2,
                                                   const int* __restrict__ rowptr,
                                                   const int2* __restrict__ erec,
                                                   const float* __restrict__ dinv,
                                                   unsigned short* __restrict__ h2,
                                                   int n) {
    __shared__ __align__(16) char sMb[RPB * 256];    // 32 rows x 128 f16 = 8 KB

    const int t    = threadIdx.x;
    const int row0 = blockIdx.x * RPB;

    // ---- Phase A: gather ----
    {
        const int r = t >> 3;                 // row-in-block 0..31
        const int b = t & 7;                  // lane-in-row  0..7 (16 feats each)
        const int d = row0 + r;
        float ga[16] = {};
        if (d < n) {
            const float wd = dinv[d];
            const uint4* P = (const uint4*)(Xh + ((size_t)d << 7)) + b * 2;
            acc16h(ga, wd * wd, P[0], P[1]);
            const int beg = rowptr[d], end = rowptr[d + 1];
            int j = beg;
            const int2 Z = make_int2(0, 0);
            int2 r0 = (j     < end) ? erec[j]     : Z;
            int2 r1 = (j + 1 < end) ? erec[j + 1] : Z;
            int2 r2 = (j + 2 < end) ? erec[j + 2] : Z;
            int2 r3 = (j + 3 < end) ? erec[j + 3] : Z;
            while (j < end) {
                const int2 c0 = r0, c1 = r1, c2 = r2, c3 = r3;
                const int jn = j + 4;
                r0 = (jn     < end) ? erec[jn]     : Z;   // prefetch next quad
                r1 = (jn + 1 < end) ? erec[jn + 1] : Z;
                r2 = (jn + 2 < end) ? erec[jn + 2] : Z;
                r3 = (jn + 3 < end) ? erec[jn + 3] : Z;
                const uint4* P0 = (const uint4*)(Xh + ((size_t)c0.x << 7)) + b * 2;
                const uint4* P1 = (const uint4*)(Xh + ((size_t)c1.x << 7)) + b * 2;
                const uint4* P2 = (const uint4*)(Xh + ((size_t)c2.x << 7)) + b * 2;
                const uint4* P3 = (const uint4*)(Xh + ((size_t)c3.x << 7)) + b * 2;
                uint4 a0 = P0[0], a1 = P0[1];
                uint4 b0 = P1[0], b1 = P1[1];
                uint4 d0 = P2[0], d1 = P2[1];
                uint4 e0 = P3[0], e1 = P3[1];
                acc16h(ga, __int_as_float(c0.y), a0, a1);  // coef 0 for tail slots
                acc16h(ga, __int_as_float(c1.y), b0, b1);
                acc16h(ga, __int_as_float(c2.y), d0, d1);
                acc16h(ga, __int_as_float(c3.y), e0, e1);
                j = jn;
            }
        }
        uint4 o0, o1;
        o0.x = pkh(ga[0],  ga[1]);  o0.y = pkh(ga[2],  ga[3]);
        o0.z = pkh(ga[4],  ga[5]);  o0.w = pkh(ga[6],  ga[7]);
        o1.x = pkh(ga[8],  ga[9]);  o1.y = pkh(ga[10], ga[11]);
        o1.z = pkh(ga[12], ga[13]); o1.w = pkh(ga[14], ga[15]);
        const int swz = (r & 7) << 4;
        *(uint4*)(sMb + ((r * 256 + b * 32)      ^ swz)) = o0;
        *(uint4*)(sMb + ((r * 256 + b * 32 + 16) ^ swz)) = o1;
    }
    __syncthreads();

    const int w  = t >> 6;                    // wave 0..3
    const int l  = t & 63;
    const int lr = l & 15;                    // frag row/col within 16-tile
    const int lk = (l >> 4) << 4;             // byte offset of this lane's k-octet
    const int sz = (lr & 7) << 4;             // swizzle for rows lr and lr+16

    // ---- Phase B: (M·X)@W1, wave w -> cols [32w, 32w+32) ----
    f4v acc[2][2] = {};
#pragma unroll
    for (int kt = 0; kt < 4; ++kt) {
        const int kb = kt * 64 + lk;
        h8 a0 = *(const h8*)(sMb + ((lr * 256 + kb)        ^ sz));
        h8 a1 = *(const h8*)(sMb + (((lr + 16) * 256 + kb) ^ sz));
        const h8* Bp = (const h8*)Wpk1 + (kt * 8 + w * 2) * 64 + l;
        h8 b0 = Bp[0];
        h8 b1 = Bp[64];
        acc[0][0] = __builtin_amdgcn_mfma_f32_16x16x32_f16(a0, b0, acc[0][0], 0, 0, 0);
        acc[0][1] = __builtin_amdgcn_mfma_f32_16x16x32_f16(a0, b1, acc[0][1], 0, 0, 0);
        acc[1][0] = __builtin_amdgcn_mfma_f32_16x16x32_f16(a1, b0, acc[1][0], 0, 0, 0);
        acc[1][1] = __builtin_amdgcn_mfma_f32_16x16x32_f16(a1, b1, acc[1][1], 0, 0, 0);
    }
    __syncthreads();                          // all sM reads done before a1 overwrite

    // ---- Phase C: bias+relu -> a1 (f16) back into the same LDS tile ----
    {
        const float bb0 = bias1[w * 32 + lr];
        const float bb1 = bias1[w * 32 + 16 + lr];
        const int c0 = (w * 32 + lr) * 2;
        const int c1 = (w * 32 + 16 + lr) * 2;
#pragma unroll
        for (int mt = 0; mt < 2; ++mt)
#pragma unroll
            for (int v = 0; v < 4; ++v) {
                const int row = mt * 16 + ((l >> 4) << 2) + v;
                const int rs  = (row & 7) << 4;
                float o0 = fmaxf(acc[mt][0][v] + bb0, 0.f);
                float o1 = fmaxf(acc[mt][1][v] + bb1, 0.f);
                *(_Float16*)(sMb + ((row * 256 + c0) ^ rs)) = (_Float16)o0;
                *(_Float16*)(sMb + ((row * 256 + c1) ^ rs)) = (_Float16)o1;
            }
    }
    __syncthreads();

    // ---- Phase D: a1@W2 -> h2, wave w -> cols [16w, 16w+16) ----
    f4v acc2[2] = {};
#pragma unroll
    for (int kt = 0; kt < 4; ++kt) {
        const int kb = kt * 64 + lk;
        h8 a0 = *(const h8*)(sMb + ((lr * 256 + kb)        ^ sz));
        h8 a1 = *(const h8*)(sMb + (((lr + 16) * 256 + kb) ^ sz));
        h8 b  = *((const h8*)Wpk2 + (kt * 4 + w) * 64 + l);
        acc2[0] = __builtin_amdgcn_mfma_f32_16x16x32_f16(a0, b, acc2[0], 0, 0, 0);
        acc2[1] = __builtin_amdgcn_mfma_f32_16x16x32_f16(a1, b, acc2[1], 0, 0, 0);
    }
#pragma unroll
    for (int mt = 0; mt < 2; ++mt)
#pragma unroll
        for (int v = 0; v < 4; ++v) {
            const int row = row0 + mt * 16 + ((l >> 4) << 2) + v;
            if (row < n) {
                _Float16 hv = (_Float16)acc2[mt][v];
                h2[(size_t)row * 64 + w * 16 + lr] = __builtin_bit_cast(unsigned short, hv);
            }
        }
}

// ---------------------------------------------------------------------------
// Layer-2 aggregation: out[d] = dinv_d^2*h2[d] + sum_e coef_e*h2[src_e] + b2.
// Pure 64-wide gather (128 B/row): 8 lanes/row, 1 uint4 (8 f16) per lane.
// ---------------------------------------------------------------------------
__global__ __launch_bounds__(256, 6) void k_out(const unsigned short* __restrict__ h2,
                                                const float* __restrict__ b2,
                                                const int* __restrict__ rowptr,
                                                const int2* __restrict__ erec,
                                                const float* __restrict__ dinv,
                                                float* __restrict__ out, int n) {
    const int t = threadIdx.x;
    const int r = t >> 3;
    const int b = t & 7;
    const int d = blockIdx.x * RPB + r;
    if (d >= n) return;

    float ga[8] = {};
    {
        const float wd = dinv[d];
        uint4 u = *((const uint4*)(h2 + ((size_t)d << 6)) + b);
        acc8h(ga, wd * wd, u);
    }
    const int beg = rowptr[d], end = rowptr[d + 1];
    int j = beg;
    const int2 Z = make_int2(0, 0);
    int2 r0 = (j     < end) ? erec[j]     : Z;
    int2 r1 = (j + 1 < end) ? erec[j + 1] : Z;
    int2 r2 = (j + 2 < end) ? erec[j + 2] : Z;
    int2 r3 = (j + 3 < end) ? erec[j + 3] : Z;
    while (j < end) {
        const int2 c0 = r0, c1 = r1, c2 = r2, c3 = r3;
        const int jn = j + 4;
        r0 = (jn     < end) ? erec[jn]     : Z;
        r1 = (jn + 1 < end) ? erec[jn + 1] : Z;
        r2 = (jn + 2 < end) ? erec[jn + 2] : Z;
        r3 = (jn + 3 < end) ? erec[jn + 3] : Z;
        uint4 a  = *((const uint4*)(h2 + ((size_t)c0.x << 6)) + b);
        uint4 u1 = *((const uint4*)(h2 + ((size_t)c1.x << 6)) + b);
        uint4 u2 = *((const uint4*)(h2 + ((size_t)c2.x << 6)) + b);
        uint4 u3 = *((const uint4*)(h2 + ((size_t)c3.x << 6)) + b);
        acc8h(ga, __int_as_float(c0.y), a);
        acc8h(ga, __int_as_float(c1.y), u1);
        acc8h(ga, __int_as_float(c2.y), u2);
        acc8h(ga, __int_as_float(c3.y), u3);
        j = jn;
    }
    const float4 bv0 = *(const float4*)&b2[b * 8];
    const float4 bv1 = *(const float4*)&b2[b * 8 + 4];
    float* O = out + (size_t)d * 64 + b * 8;
    *(float4*)O       = make_float4(ga[0] + bv0.x, ga[1] + bv0.y, ga[2] + bv0.z, ga[3] + bv0.w);
    *(float4*)(O + 4) = make_float4(ga[4] + bv1.x, ga[5] + bv1.y, ga[6] + bv1.z, ga[7] + bv1.w);
}

// ---------------------------------------------------------------------------

extern "C" void kernel_launch(void* const* d_in, const int* in_sizes, int n_in,
                              void* d_out, int out_size, void* d_ws, size_t ws_size,
                              hipStream_t stream) {
    const float* x  = (const float*)d_in[0];
    const int*   ei = (const int*)d_in[1];
    const float* W1 = (const float*)d_in[2];
    const float* b1 = (const float*)d_in[3];
    const float* W2 = (const float*)d_in[4];
    const float* b2 = (const float*)d_in[5];
    float* out = (float*)d_out;

    const int N = in_sizes[0] / 128;
    const int E = in_sizes[1] / 2;
    const int* src = ei;
    const int* dst = ei + E;
    const int NBK = (N + 255) >> 8;        // 196 for N=50000
    if (NBK > 256) return;                 // design limit (N <= 65536)

    // workspace carve (256B aligned)
    size_t off = 0;
    char* base = (char*)d_ws;
    auto carve = [&](size_t bytes) -> void* {
        void* p = base + off;
        off += (bytes + 255) & ~(size_t)255;
        return p;
    };
    int*   bcur   = (int*)carve(256 * 4);               // zeroed per call
    int*   rowptr = (int*)carve((size_t)(N + 1) * 4);
    float* dinv   = (float*)carve((size_t)N * 4);
    int2*  erec   = (int2*)carve((size_t)E * 8);
    int2*  ebuf   = (int2*)carve((size_t)256 * CAP * 8);   // bucket staging, 16.8MB
    unsigned short* xh   = (unsigned short*)carve((size_t)N * 128 * 2);
    unsigned short* h2   = (unsigned short*)carve((size_t)N * 64 * 2);
    unsigned short* Wpk1 = (unsigned short*)carve(128 * 128 * 2);
    unsigned short* Wpk2 = (unsigned short*)carve(128 * 64 * 2);

    if (off > ws_size) return;  // diagnostic guard

    // 1) f16 convert + bucket phase A + W frag-pack (one launch)
    const int nElem = N * 128;
    const int CB  = (nElem / 8 + 255) / 256;
    const int EPB = (E + PA_BLK - 1) / PA_BLK;
    hipMemsetAsync(bcur, 0, 256 * 4, stream);
    k_prep<<<CB + PA_BLK + 12, 256, 0, stream>>>(x, xh, nElem, src, dst, E,
                                                 bcur, ebuf, CB, EPB,
                                                 W1, W2, Wpk1, Wpk2);
    // 2) per-bucket sort -> rowptr/dinv/erec ; then coef fill
    k_bucket<<<NBK, 256, 0, stream>>>(ebuf, bcur, rowptr, dinv, erec, N, NBK, E);
    k_coef<<<(E + 255) / 256, 256, 0, stream>>>(erec, dinv, E);

    const int nblk = (N + RPB - 1) / RPB;
    // 3) fused layer 1 (+W2 commute): h2 = f16(relu((M xh)@W1 + b1) @ W2)
    fused_l1<<<nblk, 256, 0, stream>>>(xh, Wpk1, b1, Wpk2, rowptr, erec, dinv, h2, N);
    // 4) layer 2 aggregation: out = (M h2) + b2   (fp32 out)
    k_out<<<nblk, 256, 0, stream>>>(h2, b2, rowptr, erec, dinv, out, N);
}